// Round 3
// baseline (3245.078 us; speedup 1.0000x reference)
//
#include <hip/hip_runtime.h>

#define B_ 32
#define P_ 196
#define T_ 32
#define E_ 512
#define H_ 512
#define A_ 256
#define V_ 30000
#define FEAT_ 2048

typedef unsigned short u16;
typedef __attribute__((ext_vector_type(8))) short bf16x8;   // 8 bf16 = 4 VGPR
typedef __attribute__((ext_vector_type(4))) float fx4;

#define MFMA16 __builtin_amdgcn_mfma_f32_16x16x32_bf16

// relaxed agent-scope atomics: lower to cache-bypassing (sc0 sc1) global ops,
// coherent at L3 across XCDs -> NO buffer_wbl2/buffer_inv fences needed.
#define ALOAD(p)    __hip_atomic_load((p), __ATOMIC_RELAXED, __HIP_MEMORY_SCOPE_AGENT)
#define ASTORE(p,v) __hip_atomic_store((p), (v), __ATOMIC_RELAXED, __HIP_MEMORY_SCOPE_AGENT)

__device__ __forceinline__ u16 f2b(float f){
  unsigned u = __builtin_bit_cast(unsigned, f);
  u += 0x7FFFu + ((u >> 16) & 1u);
  return (u16)(u >> 16);
}
__device__ __forceinline__ float b2f(u16 h){
  unsigned u = ((unsigned)h) << 16;
  return __builtin_bit_cast(float, u);
}
__device__ __forceinline__ float sigm(float x){ return 1.f/(1.f + __expf(-x)); }

__device__ __forceinline__ bf16x8 aload_bf8(const u16* p){
  const unsigned* q = (const unsigned*)p;
  union { unsigned u[4]; bf16x8 v; } x;
  x.u[0] = ALOAD(q);
  x.u[1] = ALOAD(q+1);
  x.u[2] = ALOAD(q+2);
  x.u[3] = ALOAD(q+3);
  return x.v;
}

// ---------------- f32 -> bf16 convert, 8 elems/thread ----------------
__global__ void k_convert(const float* __restrict__ src, u16* __restrict__ dst, int n8){
  int i = blockIdx.x*256 + threadIdx.x;
  if (i >= n8) return;
  const float4* s = (const float4*)src + (size_t)i*2;
  float4 a = s[0], b = s[1];
  ushort4* d = (ushort4*)dst + (size_t)i*2;
  d[0] = make_ushort4(f2b(a.x), f2b(a.y), f2b(a.z), f2b(a.w));
  d[1] = make_ushort4(f2b(b.x), f2b(b.y), f2b(b.z), f2b(b.w));
}

// ---------------- embedding gather -> bf16, row r = t*32+b ----------------
__global__ void k_gather(const float* __restrict__ emb, const int* __restrict__ cap,
                         u16* __restrict__ dst){
  int r = blockIdx.x;            // 1024 rows
  int l = threadIdx.x;           // 64
  int t = r >> 5, b = r & 31;
  int c = cap[b*T_ + t];
  const float4* s = (const float4*)(emb + (size_t)c*E_) + l*2;
  float4 a = s[0], bb = s[1];
  ushort4* d = (ushort4*)(dst + (size_t)r*E_) + l*2;
  d[0] = make_ushort4(f2b(a.x), f2b(a.y), f2b(a.z), f2b(a.w));
  d[1] = make_ushort4(f2b(bb.x), f2b(bb.y), f2b(bb.z), f2b(bb.w));
}

// ---------------- Wd [256][512] -> transposed bf16 WdT[k][n] ----------------
__global__ void k_pack_wdt(const float* __restrict__ Wd, u16* __restrict__ dst){
  int i = blockIdx.x*256 + threadIdx.x;   // 512*256
  if (i >= 512*256) return;
  int n = i & 255, k = i >> 8;
  dst[i] = f2b(Wd[n*512 + k]);
}

// ---------------- pack layer-0 gate weights (permuted rows), K=1536 ----------------
__global__ void k_pack_g0(const float* __restrict__ Wih, const float* __restrict__ Whh,
                          u16* __restrict__ dst){
  int eid = blockIdx.x*256 + threadIdx.x;
  if (eid >= 6144*512) return;
  int j = eid & 7, l = (eid >> 3) & 63, frag = eid >> 9;
  int ks = frag % 12; int rest = frag / 12;
  int kw = rest & 3, q = (rest >> 2) & 3, s = rest >> 4;
  int n = q*512 + s*16 + (l & 15);
  int k = kw*384 + ks*32 + ((l >> 4) << 3) + j;
  float v = (k < 1024) ? Wih[(size_t)n*1024 + k] : Whh[(size_t)n*512 + (k - 1024)];
  dst[eid] = f2b(v);
}

// ---------------- pack layer-1 gate weights, K=1024 ----------------
__global__ void k_pack_g1(const float* __restrict__ Wih, const float* __restrict__ Whh,
                          u16* __restrict__ dst){
  int eid = blockIdx.x*256 + threadIdx.x;
  if (eid >= 4096*512) return;
  int j = eid & 7, l = (eid >> 3) & 63, frag = eid >> 9;
  int ks = frag & 7, kw = (frag >> 3) & 3, q = (frag >> 5) & 3, s = frag >> 7;
  int n = q*512 + s*16 + (l & 15);
  int k = kw*256 + ks*32 + ((l >> 4) << 3) + j;
  float v = (k < 512) ? Wih[(size_t)n*512 + k] : Whh[(size_t)n*512 + (k - 512)];
  dst[eid] = f2b(v);
}

// ---------------- permuted bias: b_ih + b_hh ----------------
__global__ void k_bias_pack(const float* __restrict__ bih, const float* __restrict__ bhh,
                            float* __restrict__ dst){
  int n = blockIdx.x*256 + threadIdx.x;
  if (n >= 2048) return;
  int c = n & 15, q = (n >> 4) & 3, s = n >> 6;
  int orig = q*512 + s*16 + c;
  dst[n] = bih[orig] + bhh[orig];
}

// ---------------- generic bf16 MFMA GEMM: C = A[M,K] @ W[N,K]^T + bias ----------------
// MODE 0: relu -> bf16   1: -> bf16   2: -> f32   3: clip±10 -> f32, row remap (t,b)->(b,t)
// BN: n-tile (64 or 128); m-tile fixed 128.
template<int MODE, int BN>
__launch_bounds__(256)
__global__ void k_gemm(const u16* __restrict__ A, const u16* __restrict__ W,
                       const float* __restrict__ bias, float* __restrict__ outF,
                       u16* __restrict__ outB, int M, int N, int K){
  constexpr int NI = BN/32;     // 16-frags per wave-col
  __shared__ __align__(16) u16 As[128][40];
  __shared__ __align__(16) u16 Bs[BN][40];
  int tid = threadIdx.x;
  int l = tid & 63, w = tid >> 6;
  int wr = w >> 1, wc = w & 1;
  int m0 = blockIdx.y * 128, n0 = blockIdx.x * BN;
  fx4 acc[4][NI];
  #pragma unroll
  for (int i=0;i<4;i++)
    #pragma unroll
    for (int j=0;j<NI;j++) acc[i][j] = (fx4){0.f,0.f,0.f,0.f};
  int r = tid >> 2, seg = tid & 3;
  int lr = l & 15, lg = l >> 4;
  for (int k0 = 0; k0 < K; k0 += 32){
    *(uint4*)&As[r][seg*8]    = *(const uint4*)(A + (size_t)(m0 + r)*K + k0 + seg*8);
    *(uint4*)&As[r+64][seg*8] = *(const uint4*)(A + (size_t)(m0 + r + 64)*K + k0 + seg*8);
    uint4 z = {0u,0u,0u,0u};
    int rb = n0 + r;
    *(uint4*)&Bs[r][seg*8] = (rb < N) ? *(const uint4*)(W + (size_t)rb*K + k0 + seg*8) : z;
    if constexpr (BN == 128)
      *(uint4*)&Bs[r+64][seg*8] = (rb+64 < N) ? *(const uint4*)(W + (size_t)(rb+64)*K + k0 + seg*8) : z;
    __syncthreads();
    bf16x8 av[4], bv[NI];
    #pragma unroll
    for (int mi=0; mi<4; mi++) av[mi] = *(const bf16x8*)&As[wr*64 + mi*16 + lr][lg*8];
    #pragma unroll
    for (int ni=0; ni<NI; ni++) bv[ni] = *(const bf16x8*)&Bs[wc*(BN/2) + ni*16 + lr][lg*8];
    #pragma unroll
    for (int mi=0; mi<4; mi++)
      #pragma unroll
      for (int ni=0; ni<NI; ni++)
        acc[mi][ni] = MFMA16(av[mi], bv[ni], acc[mi][ni], 0, 0, 0);
    __syncthreads();
  }
  #pragma unroll
  for (int mi=0; mi<4; mi++)
    #pragma unroll
    for (int ni=0; ni<NI; ni++){
      int col = n0 + wc*(BN/2) + ni*16 + lr;
      if (col >= N) continue;
      float bvs = bias[col];
      #pragma unroll
      for (int reg=0; reg<4; reg++){
        int rowm = m0 + wr*64 + mi*16 + lg*4 + reg;
        float v = acc[mi][ni][reg] + bvs;
        if (MODE == 0){ v = fmaxf(v, 0.f); outB[(size_t)rowm*N + col] = f2b(v); }
        else if (MODE == 1){ outB[(size_t)rowm*N + col] = f2b(v); }
        else if (MODE == 2){ outF[(size_t)rowm*N + col] = v; }
        else {
          v = fminf(fmaxf(v, -10.f), 10.f);
          int bb = rowm & 31, tt = rowm >> 5;
          outF[(size_t)(bb*T_ + tt)*V_ + col] = v;
        }
      }
    }
}

// ---------------- LayerNorm over 512 (bf16 in/out), 1 wave/row ----------------
__global__ void k_ln1(const u16* __restrict__ pre, const float* __restrict__ g,
                      const float* __restrict__ bt, u16* __restrict__ enc){
  int row = blockIdx.x; int l = threadIdx.x;
  bf16x8 vv = *(const bf16x8*)(pre + (size_t)row*E_ + l*8);
  float x[8]; float s = 0.f;
  #pragma unroll
  for (int i=0;i<8;i++){ x[i] = b2f((u16)vv[i]); s += x[i]; }
  #pragma unroll
  for (int off=32; off; off>>=1) s += __shfl_xor(s, off, 64);
  float mean = s * (1.f/512.f);
  float vs = 0.f;
  #pragma unroll
  for (int i=0;i<8;i++){ float d = x[i]-mean; vs += d*d; }
  #pragma unroll
  for (int off=32; off; off>>=1) vs += __shfl_xor(vs, off, 64);
  float inv = rsqrtf(vs*(1.f/512.f) + 1e-5f);
  int c0 = l*8;
  u16 o[8];
  #pragma unroll
  for (int i=0;i<8;i++) o[i] = f2b((x[i]-mean)*inv*g[c0+i] + bt[c0+i]);
  ushort4* d = (ushort4*)(enc + (size_t)row*E_ + c0);
  d[0] = make_ushort4(o[0],o[1],o[2],o[3]);
  d[1] = make_ushort4(o[4],o[5],o[6],o[7]);
}

// ---------------- LayerNorm over 256 + relu (f32 in, bf16 out) ----------------
__global__ void k_ln2(const float* __restrict__ pre1, const float* __restrict__ g,
                      const float* __restrict__ bb, u16* __restrict__ hid){
  int row = blockIdx.x; int l = threadIdx.x;
  float4 v = *(const float4*)(pre1 + (size_t)row*256 + l*4);
  float x[4] = {v.x, v.y, v.z, v.w};
  float s = x[0]+x[1]+x[2]+x[3];
  #pragma unroll
  for (int off=32; off; off>>=1) s += __shfl_xor(s, off, 64);
  float mean = s * (1.f/256.f);
  float vs = 0.f;
  #pragma unroll
  for (int i=0;i<4;i++){ float d = x[i]-mean; vs += d*d; }
  #pragma unroll
  for (int off=32; off; off>>=1) vs += __shfl_xor(vs, off, 64);
  float inv = rsqrtf(vs*(1.f/256.f) + 1e-5f);
  int c0 = l*4;
  u16 o[4];
  #pragma unroll
  for (int i=0;i<4;i++) o[i] = f2b(fmaxf((x[i]-mean)*inv*g[c0+i] + bb[c0+i], 0.f));
  *(ushort4*)(hid + (size_t)row*256 + c0) = make_ushort4(o[0],o[1],o[2],o[3]);
}

// ---------------- fused gates GEMM + LSTM cell (device fn, one phase) ----------------
// G=0: A stride 1536, K=1536; writes h0 -> wd0[b*1024+h] (atomic), wd1[b*1536+1024+h] (atomic)
// G=1: A stride 1024, K=1024; writes h1 -> wd0[b*1024+512+h] (atomic), wd1=h1all plain
template<int G>
__device__ __forceinline__ void gates_phase(int s, int tid, int t,
    const u16* __restrict__ xhA, const u16* __restrict__ Wpk,
    const float* __restrict__ biasp, float (&creg)[2],
    u16* __restrict__ wd0, u16* __restrict__ wd1,
    float (&part)[4][32][16], float (&gsum)[4][32][16])
{
  constexpr int NKS = (G == 0) ? 12 : 8;
  constexpr int STRIDE = (G == 0) ? 1536 : 1024;
  int l = tid & 63, kw = tid >> 6;
  int lr = l & 15, lg = l >> 4;
  bf16x8 a[2][NKS];
  #pragma unroll
  for (int mi=0;mi<2;mi++)
    #pragma unroll
    for (int ks=0;ks<NKS;ks++){
      int bb = mi*16 + lr;
      int k = kw*(NKS*32) + ks*32 + lg*8;
      a[mi][ks] = aload_bf8(xhA + bb*STRIDE + k);
    }
  for (int q=0;q<4;q++){
    fx4 acc0 = (fx4){0,0,0,0}, acc1 = (fx4){0,0,0,0};
    const u16* wp = Wpk + (size_t)(((s*4+q)*4+kw)*NKS)*512 + l*8;
    #pragma unroll
    for (int ks=0;ks<NKS;ks++){
      bf16x8 bf8 = *(const bf16x8*)(wp + ks*512);
      acc0 = MFMA16(a[0][ks], bf8, acc0, 0,0,0);
      acc1 = MFMA16(a[1][ks], bf8, acc1, 0,0,0);
    }
    #pragma unroll
    for (int reg=0;reg<4;reg++){
      part[kw][lg*4+reg][lr]    = acc0[reg];
      part[kw][16+lg*4+reg][lr] = acc1[reg];
    }
    __syncthreads();
    #pragma unroll
    for (int pp=0;pp<2;pp++){
      int pid = tid + pp*256;
      int bb = pid >> 4, c = pid & 15;
      gsum[q][bb][c] = part[0][bb][c]+part[1][bb][c]+part[2][bb][c]+part[3][bb][c]
                     + biasp[s*64 + q*16 + c];
    }
    __syncthreads();
  }
  // cell: thread handles (bb, c2, c2+1) -> pack one dword store
  {
    int bb = tid >> 3, c2 = (tid & 7)*2;
    int h = s*16 + c2;
    float gi0 = gsum[0][bb][c2],   gf0 = gsum[1][bb][c2],   gg0 = gsum[2][bb][c2],   go0 = gsum[3][bb][c2];
    float gi1 = gsum[0][bb][c2+1], gf1 = gsum[1][bb][c2+1], gg1 = gsum[2][bb][c2+1], go1 = gsum[3][bb][c2+1];
    float cn0 = sigm(gf0)*creg[0] + sigm(gi0)*tanhf(gg0); creg[0] = cn0;
    float cn1 = sigm(gf1)*creg[1] + sigm(gi1)*tanhf(gg1); creg[1] = cn1;
    float hn0 = sigm(go0)*tanhf(cn0);
    float hn1 = sigm(go1)*tanhf(cn1);
    unsigned hw = (unsigned)f2b(hn0) | ((unsigned)f2b(hn1) << 16);
    if (G == 0){
      ASTORE((unsigned*)(wd0 + bb*1024 + h), hw);
      ASTORE((unsigned*)(wd1 + bb*1536 + 1024 + h), hw);
    } else {
      ASTORE((unsigned*)(wd0 + bb*1024 + 512 + h), hw);
      *(unsigned*)(wd1 + (size_t)(t*32 + bb)*512 + h) = hw;   // h1all: cross-kernel, plain
    }
  }
}

// ---------------- persistent recurrence: 32 blocks, fence-free grid barrier ----------------
__launch_bounds__(256)
__global__ void k_recur(
    const u16* __restrict__ att1b, const u16* __restrict__ enc16,
    const u16* __restrict__ WdT, const float* __restrict__ bd,
    const float* __restrict__ Wf, const float* __restrict__ bfp,
    const u16* __restrict__ embs,
    const u16* __restrict__ Wg0pk, const float* __restrict__ bias0p,
    const u16* __restrict__ Wg1pk, const float* __restrict__ bias1p,
    u16* __restrict__ xh0, u16* __restrict__ xh1,
    u16* __restrict__ h1all, unsigned* __restrict__ sync)
{
  int bid = blockIdx.x, tid = threadIdx.x;
  int l = tid & 63, w = tid >> 6;
  __shared__ float a2[256], ev[256], red[8], wfv[256], bdv[256];
  __shared__ float h1s[512];
  __shared__ float a2p[2][256];
  __shared__ float part[4][32][16];
  __shared__ float gsum[4][32][16];
  wfv[tid] = Wf[tid];
  bdv[tid] = bd[tid];
  float bf0 = bfp[0];
  float c0reg[2] = {0.f, 0.f}, c1reg[2] = {0.f, 0.f};
  unsigned gen = 0;
  int b = bid, s = bid;
  unsigned* flags = sync;          // flags[bid*16]
  unsigned* go    = sync + 512;

  auto gsync = [&](){
    asm volatile("s_waitcnt vmcnt(0)" ::: "memory");   // each wave drains its stores
    __syncthreads();                                   // => whole block drained
    ++gen;
    if (tid == 0) ASTORE(&flags[bid*16], gen);
    if (bid == 0){
      if (tid < 32){
        while (ALOAD(&flags[tid*16]) < gen) __builtin_amdgcn_s_sleep(1);
      }
      __syncthreads();
      if (tid == 0) ASTORE(go, gen);
    }
    if (tid == 0){
      while (ALOAD(go) < gen) __builtin_amdgcn_s_sleep(1);
    }
    __syncthreads();
  };

  for (int t = 0; t < T_; ++t){
    int pt = t & 1;
    u16* xh0cur = xh0 + pt*32*1536;
    u16* xh0nxt = xh0 + (1-pt)*32*1536;
    u16* xh1cur = xh1 + pt*32*1024;
    u16* xh1nxt = xh1 + (1-pt)*32*1024;

    // ================= ATT phase (block = batch b) =================
    {
      // h1_prev -> LDS (f32)
      unsigned hv = ALOAD((const unsigned*)(xh1cur + (size_t)b*1024 + 512) + tid);
      h1s[tid*2]   = b2f((u16)(hv & 0xFFFFu));
      h1s[tid*2+1] = b2f((u16)(hv >> 16));
      __syncthreads();
      // att2 = h1 @ Wd^T (k-split halves over thread groups)
      {
        int n2 = tid & 127, kh = tid >> 7;
        float acc0 = 0.f, acc1 = 0.f;
        const unsigned* wp = (const unsigned*)WdT + (size_t)kh*256*128 + n2;
        #pragma unroll 8
        for (int kk = 0; kk < 256; ++kk){
          unsigned v = wp[(size_t)kk*128];
          float hk = h1s[kh*256 + kk];
          acc0 += hk * b2f((u16)(v & 0xFFFFu));
          acc1 += hk * b2f((u16)(v >> 16));
        }
        a2p[kh][n2*2]   = acc0;
        a2p[kh][n2*2+1] = acc1;
      }
      __syncthreads();
      a2[tid] = a2p[0][tid] + a2p[1][tid] + bdv[tid];
      __syncthreads();
      // e scores (wave w handles 49 pixels)
      for (int pi = 0; pi < 49; ++pi){
        int p = w*49 + pi;
        ushort4 av4 = *(const ushort4*)(att1b + (size_t)(b*P_ + p)*A_ + l*4);
        int j0 = l*4;
        float sum = fmaxf(b2f(av4.x)+a2[j0],  0.f)*wfv[j0]
                  + fmaxf(b2f(av4.y)+a2[j0+1],0.f)*wfv[j0+1]
                  + fmaxf(b2f(av4.z)+a2[j0+2],0.f)*wfv[j0+2]
                  + fmaxf(b2f(av4.w)+a2[j0+3],0.f)*wfv[j0+3];
        #pragma unroll
        for (int off=32; off; off>>=1) sum += __shfl_xor(sum, off, 64);
        if (l == 0) ev[p] = sum + bf0;
      }
      __syncthreads();
      float v = (tid < P_) ? ev[tid] : -1e30f;
      float m = v;
      #pragma unroll
      for (int off=32; off; off>>=1) m = fmaxf(m, __shfl_xor(m, off, 64));
      if (l == 0) red[w] = m;
      __syncthreads();
      m = fmaxf(fmaxf(red[0],red[1]), fmaxf(red[2],red[3]));
      float ex = (tid < P_) ? __expf(v - m) : 0.f;
      __syncthreads();
      ev[tid] = ex;
      float ss = ex;
      #pragma unroll
      for (int off=32; off; off>>=1) ss += __shfl_xor(ss, off, 64);
      if (l == 0) red[4+w] = ss;
      __syncthreads();
      float inv = 1.f/(red[4]+red[5]+red[6]+red[7]);
      // ctx: thread handles bf16 column-pair tid
      {
        float acc0 = 0.f, acc1 = 0.f;
        const unsigned* ep = (const unsigned*)(enc16 + (size_t)b*P_*E_) + tid;
        for (int p = 0; p < P_; ++p){
          unsigned vv = ep[(size_t)p*256];
          float al = ev[p];
          acc0 += al * b2f((u16)(vv & 0xFFFFu));
          acc1 += al * b2f((u16)(vv >> 16));
        }
        unsigned o = (unsigned)f2b(acc0*inv) | ((unsigned)f2b(acc1*inv) << 16);
        ASTORE((unsigned*)(xh0cur + (size_t)b*1536 + 512) + tid, o);
      }
      // emb_t copy
      unsigned ew = ((const unsigned*)(embs + (size_t)(t*32+b)*E_))[tid];
      ASTORE(((unsigned*)(xh0cur + (size_t)b*1536)) + tid, ew);
    }
    gsync();
    // ================= GATES0 (block = h-slice s) =================
    gates_phase<0>(s, tid, t, xh0cur, Wg0pk, bias0p, c0reg, xh1cur, xh0nxt, part, gsum);
    gsync();
    // ================= GATES1 =================
    gates_phase<1>(s, tid, t, xh1cur, Wg1pk, bias1p, c1reg, xh1nxt, h1all, part, gsum);
    gsync();
  }
}

extern "C" void kernel_launch(void* const* d_in, const int* in_sizes, int n_in,
                              void* d_out, int out_size, void* d_ws, size_t ws_size,
                              hipStream_t stream){
  (void)in_sizes; (void)n_in; (void)out_size; (void)ws_size;
  const float* features = (const float*)d_in[0];
  const int*   captions = (const int*)d_in[1];
  const float* Wad  = (const float*)d_in[2];
  const float* bad  = (const float*)d_in[3];
  const float* g_ad = (const float*)d_in[4];
  const float* b_ad = (const float*)d_in[5];
  const float* We   = (const float*)d_in[6];
  const float* be   = (const float*)d_in[7];
  const float* Wd   = (const float*)d_in[8];
  const float* bd   = (const float*)d_in[9];
  const float* Wf   = (const float*)d_in[10];
  const float* bfp  = (const float*)d_in[11];
  const float* emb  = (const float*)d_in[12];
  const float* W_ih0 = (const float*)d_in[13];
  const float* W_hh0 = (const float*)d_in[14];
  const float* b_ih0 = (const float*)d_in[15];
  const float* b_hh0 = (const float*)d_in[16];
  const float* W_ih1 = (const float*)d_in[17];
  const float* W_hh1 = (const float*)d_in[18];
  const float* b_ih1 = (const float*)d_in[19];
  const float* b_hh1 = (const float*)d_in[20];
  const float* W1  = (const float*)d_in[21];
  const float* b1  = (const float*)d_in[22];
  const float* g1  = (const float*)d_in[23];
  const float* bb1 = (const float*)d_in[24];
  const float* W2  = (const float*)d_in[25];
  const float* b2  = (const float*)d_in[26];
  float* out = (float*)d_out;

  char* wsb = (char*)d_ws;
  size_t off = 0;
  auto alloc = [&](size_t bytes)->char*{
    char* p = wsb + off; off += (bytes + 255) & ~(size_t)255; return p;
  };
  u16* fb16    = (u16*)alloc((size_t)6272*2048*2);
  u16* Wad16   = (u16*)alloc((size_t)512*2048*2);
  u16* We16    = (u16*)alloc((size_t)256*512*2);
  u16* W1_16   = (u16*)alloc((size_t)256*512*2);
  u16* W2_16   = (u16*)alloc((size_t)30000*256*2);
  u16* WdT16   = (u16*)alloc((size_t)512*256*2);
  u16* Wg0pk   = (u16*)alloc((size_t)2048*1536*2);
  u16* Wg1pk   = (u16*)alloc((size_t)2048*1024*2);
  float* bias0p = (float*)alloc(2048*4);
  float* bias1p = (float*)alloc(2048*4);
  u16* embs16  = (u16*)alloc((size_t)1024*512*2);
  u16* pre16   = (u16*)alloc((size_t)6272*512*2);
  u16* enc16   = (u16*)alloc((size_t)6272*512*2);
  u16* att1_16 = (u16*)alloc((size_t)6272*256*2);
  u16* xh0     = (u16*)alloc((size_t)2*32*1536*2);   // start of zeroed region
  u16* xh1     = (u16*)alloc((size_t)2*32*1024*2);
  unsigned* syncw = (unsigned*)alloc(4096);          // flags[32*16] + go @ +512
  u16* h1all16 = (u16*)alloc((size_t)1024*512*2);
  float* pre1  = (float*)alloc((size_t)1024*256*4);
  u16* hid16   = (u16*)alloc((size_t)1024*256*2);

  auto cdiv = [](int a, int b){ return (a+b-1)/b; };

  // zero recurrent state + sync area (contiguous: 196608 + 131072 + 4096)
  hipMemsetAsync(xh0, 0, 196608 + 131072 + 4096, stream);

  // prep: converts / packs / gather
  k_convert<<<cdiv(6272*2048/8,256),256,0,stream>>>(features, fb16, 6272*2048/8);
  k_convert<<<cdiv(512*2048/8,256),256,0,stream>>>(Wad, Wad16, 512*2048/8);
  k_convert<<<cdiv(256*512/8,256),256,0,stream>>>(We, We16, 256*512/8);
  k_convert<<<cdiv(256*512/8,256),256,0,stream>>>(W1, W1_16, 256*512/8);
  k_convert<<<cdiv(30000*256/8,256),256,0,stream>>>(W2, W2_16, 30000*256/8);
  k_pack_wdt<<<cdiv(512*256,256),256,0,stream>>>(Wd, WdT16);
  k_pack_g0<<<cdiv(6144*512,256),256,0,stream>>>(W_ih0, W_hh0, Wg0pk);
  k_pack_g1<<<cdiv(4096*512,256),256,0,stream>>>(W_ih1, W_hh1, Wg1pk);
  k_bias_pack<<<8,256,0,stream>>>(b_ih0, b_hh0, bias0p);
  k_bias_pack<<<8,256,0,stream>>>(b_ih1, b_hh1, bias1p);
  k_gather<<<1024,64,0,stream>>>(emb, captions, embs16);

  // encoder: adapter GEMM (+relu), LN, att1 GEMM  (BN=64 -> 2 blocks/CU)
  k_gemm<0,64><<<dim3(8,49),256,0,stream>>>(fb16, Wad16, bad, nullptr, pre16, 6272, 512, 2048);
  k_ln1<<<6272,64,0,stream>>>(pre16, g_ad, b_ad, enc16);
  k_gemm<1,64><<<dim3(4,49),256,0,stream>>>(enc16, We16, be, nullptr, att1_16, 6272, 256, 512);

  // persistent recurrence (32 co-resident blocks, fence-free barrier)
  k_recur<<<32,256,0,stream>>>(att1_16, enc16, WdT16, bd, Wf, bfp, embs16,
                               Wg0pk, bias0p, Wg1pk, bias1p,
                               xh0, xh1, h1all16, syncw);

  // batched output head
  k_gemm<2,64><<<dim3(4,8),256,0,stream>>>(h1all16, W1_16, b1, pre1, nullptr, 1024, 256, 512);
  k_ln2<<<1024,64,0,stream>>>(pre1, g1, bb1, hid16);
  k_gemm<3,128><<<dim3(235,8),256,0,stream>>>(hid16, W2_16, b2, out, nullptr, 1024, 30000, 256);
}

// Round 5
// 2546.441 us; speedup vs baseline: 1.2744x; 1.2744x over previous
//
#include <hip/hip_runtime.h>

#define B_ 32
#define P_ 196
#define T_ 32
#define E_ 512
#define H_ 512
#define A_ 256
#define V_ 30000
#define FEAT_ 2048

typedef unsigned short u16;
typedef __attribute__((ext_vector_type(8))) short bf16x8;   // 8 bf16 = 4 VGPR
typedef __attribute__((ext_vector_type(4))) float fx4;

#define MFMA16 __builtin_amdgcn_mfma_f32_16x16x32_bf16

__device__ __forceinline__ u16 f2b(float f){
  unsigned u = __builtin_bit_cast(unsigned, f);
  u += 0x7FFFu + ((u >> 16) & 1u);
  return (u16)(u >> 16);
}
__device__ __forceinline__ float b2f(u16 h){
  unsigned u = ((unsigned)h) << 16;
  return __builtin_bit_cast(float, u);
}
__device__ __forceinline__ float sigm(float x){ return 1.f/(1.f + __expf(-x)); }

// ---------------- f32 -> bf16 convert ----------------
__global__ void k_convert(const float* __restrict__ src, u16* __restrict__ dst, int n8){
  int i = blockIdx.x*256 + threadIdx.x;
  if (i >= n8) return;
  const float4* s = (const float4*)src + (size_t)i*2;
  float4 a = s[0], b = s[1];
  ushort4* d = (ushort4*)dst + (size_t)i*2;
  d[0] = make_ushort4(f2b(a.x), f2b(a.y), f2b(a.z), f2b(a.w));
  d[1] = make_ushort4(f2b(b.x), f2b(b.y), f2b(b.z), f2b(b.w));
}

// ---------------- embedding gather -> bf16, row r = t*32+b ----------------
__global__ void k_gather(const float* __restrict__ emb, const int* __restrict__ cap,
                         u16* __restrict__ dst){
  int r = blockIdx.x, l = threadIdx.x;
  int t = r >> 5, b = r & 31;
  int c = cap[b*T_ + t];
  const float4* s = (const float4*)(emb + (size_t)c*E_) + l*2;
  float4 a = s[0], bb = s[1];
  ushort4* d = (ushort4*)(dst + (size_t)r*E_) + l*2;
  d[0] = make_ushort4(f2b(a.x), f2b(a.y), f2b(a.z), f2b(a.w));
  d[1] = make_ushort4(f2b(bb.x), f2b(bb.y), f2b(bb.z), f2b(bb.w));
}

// ---------------- Wd [256n][512k] -> Wd2[kp][n] u32 of (bf16 k=2kp, k=2kp+1) ----------------
__global__ void k_pack_wd2(const float* __restrict__ Wd, unsigned* __restrict__ dst){
  int i = blockIdx.x*256 + threadIdx.x;
  if (i >= 256*256) return;
  int n = i & 255, kp = i >> 8;
  unsigned lo = f2b(Wd[n*512 + 2*kp]);
  unsigned hi = f2b(Wd[n*512 + 2*kp + 1]);
  dst[i] = lo | (hi << 16);
}

// ---------------- pack layer-0 gate weights (permuted rows), K=1536 ----------------
// permuted col n' = s*64+q*16+r  <->  orig row = q*512+s*16+r
__global__ void k_pack_g0(const float* __restrict__ Wih, const float* __restrict__ Whh,
                          u16* __restrict__ dst){
  int eid = blockIdx.x*256 + threadIdx.x;
  if (eid >= 6144*512) return;
  int j = eid & 7, l = (eid >> 3) & 63, frag = eid >> 9;
  int ks = frag % 12; int rest = frag / 12;
  int kw = rest & 3, q = (rest >> 2) & 3, s = rest >> 4;
  int n = q*512 + s*16 + (l & 15);
  int k = kw*384 + ks*32 + ((l >> 4) << 3) + j;
  float v = (k < 1024) ? Wih[(size_t)n*1024 + k] : Whh[(size_t)n*512 + (k - 1024)];
  dst[eid] = f2b(v);
}

// ---------------- pack layer-1 partial weights, per-slice K=32 frags ----------------
// eid = (s*128 + nf)*512 + l*8 + j ; n' = nf*16+(l&15) ; k = (l>>4)*8+j in [0,32)
// k<16 -> Wih1[orig][s*16+k] (h0 slice), else Whh1[orig][s*16+k-16] (h1 slice)
__global__ void k_pack_w1p(const float* __restrict__ Wih, const float* __restrict__ Whh,
                           u16* __restrict__ dst){
  int eid = blockIdx.x*256 + threadIdx.x;
  if (eid >= 32*128*512) return;
  int j = eid & 7, l = (eid >> 3) & 63, f = eid >> 9;
  int nf = f & 127, s = f >> 7;
  int np = nf*16 + (l & 15);
  int k = ((l >> 4) << 3) + j;
  int orig = ((np >> 4) & 3)*512 + (np >> 6)*16 + (np & 15);
  float v = (k < 16) ? Wih[(size_t)orig*512 + s*16 + k]
                     : Whh[(size_t)orig*512 + s*16 + (k - 16)];
  dst[eid] = f2b(v);
}

// ---------------- permuted bias: b_ih + b_hh ----------------
__global__ void k_bias_pack(const float* __restrict__ bih, const float* __restrict__ bhh,
                            float* __restrict__ dst){
  int n = blockIdx.x*256 + threadIdx.x;
  if (n >= 2048) return;
  int c = n & 15, q = (n >> 4) & 3, s = n >> 6;
  int orig = q*512 + s*16 + c;
  dst[n] = bih[orig] + bhh[orig];
}

// ---------------- generic bf16 MFMA GEMM: C = A[M,K] @ W[N,K]^T + bias ----------------
template<int MODE, int BN>
__launch_bounds__(256)
__global__ void k_gemm(const u16* __restrict__ A, const u16* __restrict__ W,
                       const float* __restrict__ bias, float* __restrict__ outF,
                       u16* __restrict__ outB, int M, int N, int K){
  constexpr int NI = BN/32;
  __shared__ __align__(16) u16 As[128][40];
  __shared__ __align__(16) u16 Bs[BN][40];
  int tid = threadIdx.x;
  int l = tid & 63, w = tid >> 6;
  int wr = w >> 1, wc = w & 1;
  int m0 = blockIdx.y * 128, n0 = blockIdx.x * BN;
  fx4 acc[4][NI];
  #pragma unroll
  for (int i=0;i<4;i++)
    #pragma unroll
    for (int j=0;j<NI;j++) acc[i][j] = (fx4){0.f,0.f,0.f,0.f};
  int r = tid >> 2, seg = tid & 3;
  int lr = l & 15, lg = l >> 4;
  for (int k0 = 0; k0 < K; k0 += 32){
    *(uint4*)&As[r][seg*8]    = *(const uint4*)(A + (size_t)(m0 + r)*K + k0 + seg*8);
    *(uint4*)&As[r+64][seg*8] = *(const uint4*)(A + (size_t)(m0 + r + 64)*K + k0 + seg*8);
    uint4 z = {0u,0u,0u,0u};
    int rb = n0 + r;
    *(uint4*)&Bs[r][seg*8] = (rb < N) ? *(const uint4*)(W + (size_t)rb*K + k0 + seg*8) : z;
    if constexpr (BN == 128)
      *(uint4*)&Bs[r+64][seg*8] = (rb+64 < N) ? *(const uint4*)(W + (size_t)(rb+64)*K + k0 + seg*8) : z;
    __syncthreads();
    bf16x8 av[4], bv[NI];
    #pragma unroll
    for (int mi=0; mi<4; mi++) av[mi] = *(const bf16x8*)&As[wr*64 + mi*16 + lr][lg*8];
    #pragma unroll
    for (int ni=0; ni<NI; ni++) bv[ni] = *(const bf16x8*)&Bs[wc*(BN/2) + ni*16 + lr][lg*8];
    #pragma unroll
    for (int mi=0; mi<4; mi++)
      #pragma unroll
      for (int ni=0; ni<NI; ni++)
        acc[mi][ni] = MFMA16(av[mi], bv[ni], acc[mi][ni], 0, 0, 0);
    __syncthreads();
  }
  #pragma unroll
  for (int mi=0; mi<4; mi++)
    #pragma unroll
    for (int ni=0; ni<NI; ni++){
      int col = n0 + wc*(BN/2) + ni*16 + lr;
      if (col >= N) continue;
      float bvs = bias[col];
      #pragma unroll
      for (int reg=0; reg<4; reg++){
        int rowm = m0 + wr*64 + mi*16 + lg*4 + reg;
        float v = acc[mi][ni][reg] + bvs;
        if (MODE == 0){ v = fmaxf(v, 0.f); outB[(size_t)rowm*N + col] = f2b(v); }
        else if (MODE == 1){ outB[(size_t)rowm*N + col] = f2b(v); }
        else if (MODE == 2){ outF[(size_t)rowm*N + col] = v; }
        else {
          v = fminf(fmaxf(v, -10.f), 10.f);
          int bb = rowm & 31, tt = rowm >> 5;
          outF[(size_t)(bb*T_ + tt)*V_ + col] = v;
        }
      }
    }
}

// ---------------- LayerNorm over 512 (bf16 in/out) ----------------
__global__ void k_ln1(const u16* __restrict__ pre, const float* __restrict__ g,
                      const float* __restrict__ bt, u16* __restrict__ enc){
  int row = blockIdx.x; int l = threadIdx.x;
  bf16x8 vv = *(const bf16x8*)(pre + (size_t)row*E_ + l*8);
  float x[8]; float s = 0.f;
  #pragma unroll
  for (int i=0;i<8;i++){ x[i] = b2f((u16)vv[i]); s += x[i]; }
  #pragma unroll
  for (int off=32; off; off>>=1) s += __shfl_xor(s, off, 64);
  float mean = s * (1.f/512.f);
  float vs = 0.f;
  #pragma unroll
  for (int i=0;i<8;i++){ float d = x[i]-mean; vs += d*d; }
  #pragma unroll
  for (int off=32; off; off>>=1) vs += __shfl_xor(vs, off, 64);
  float inv = rsqrtf(vs*(1.f/512.f) + 1e-5f);
  int c0 = l*8;
  u16 o[8];
  #pragma unroll
  for (int i=0;i<8;i++) o[i] = f2b((x[i]-mean)*inv*g[c0+i] + bt[c0+i]);
  ushort4* d = (ushort4*)(enc + (size_t)row*E_ + c0);
  d[0] = make_ushort4(o[0],o[1],o[2],o[3]);
  d[1] = make_ushort4(o[4],o[5],o[6],o[7]);
}

// ---------------- LayerNorm over 256 + relu (f32 in, bf16 out) ----------------
__global__ void k_ln2(const float* __restrict__ pre1, const float* __restrict__ g,
                      const float* __restrict__ bb, u16* __restrict__ hid){
  int row = blockIdx.x; int l = threadIdx.x;
  float4 v = *(const float4*)(pre1 + (size_t)row*256 + l*4);
  float x[4] = {v.x, v.y, v.z, v.w};
  float s = x[0]+x[1]+x[2]+x[3];
  #pragma unroll
  for (int off=32; off; off>>=1) s += __shfl_xor(s, off, 64);
  float mean = s * (1.f/256.f);
  float vs = 0.f;
  #pragma unroll
  for (int i=0;i<4;i++){ float d = x[i]-mean; vs += d*d; }
  #pragma unroll
  for (int off=32; off; off>>=1) vs += __shfl_xor(vs, off, 64);
  float inv = rsqrtf(vs*(1.f/256.f) + 1e-5f);
  int c0 = l*4;
  u16 o[4];
  #pragma unroll
  for (int i=0;i<4;i++) o[i] = f2b(fmaxf((x[i]-mean)*inv*g[c0+i] + bb[c0+i], 0.f));
  *(ushort4*)(hid + (size_t)row*256 + c0) = make_ushort4(o[0],o[1],o[2],o[3]);
}

// ---------------- LY: finish gates1(t-1) -> h1(t-1); att2; attention; write [emb|ctx] ----------------
// block = batch b. t in [0,32]; t==32 does only the finish.
__launch_bounds__(256)
__global__ void k_ly(const float* __restrict__ part1, const float* __restrict__ bias1p,
                     float* __restrict__ c1buf, u16* __restrict__ h1all,
                     const unsigned* __restrict__ Wd2, const float* __restrict__ bd,
                     const u16* __restrict__ att1b, const u16* __restrict__ enc16,
                     const float* __restrict__ Wf, const float* __restrict__ bfp,
                     const u16* __restrict__ embs, u16* __restrict__ xh0cur, int t){
  int b = blockIdx.x, tid = threadIdx.x;
  int l = tid & 63, wid = tid >> 6;
  __shared__ float g1s[2048];
  __shared__ float h1s[512];
  __shared__ float a2[256], ev[256], red[8], wfv[256], bdv[256];
  wfv[tid] = Wf[tid];
  bdv[tid] = bd[tid];
  float bf0 = bfp[0];

  if (t > 0){
    float acc[8];
    #pragma unroll
    for (int j=0;j<8;j++) acc[j] = bias1p[tid + j*256];
    #pragma unroll 4
    for (int s=0;s<32;s++){
      const float* pp = part1 + ((size_t)(s*32 + b))*2048 + tid;
      #pragma unroll
      for (int j=0;j<8;j++) acc[j] += pp[j*256];
    }
    #pragma unroll
    for (int j=0;j<8;j++) g1s[tid + j*256] = acc[j];
    __syncthreads();
    int h0i = tid*2;
    float hh[2];
    #pragma unroll
    for (int e2=0;e2<2;e2++){
      int h = h0i + e2, s4 = h >> 4, c = h & 15, base = s4*64 + c;
      float gi = g1s[base], gf = g1s[base+16], gg = g1s[base+32], go = g1s[base+48];
      float cold = c1buf[b*512 + h];
      float cn = sigm(gf)*cold + sigm(gi)*tanhf(gg);
      c1buf[b*512 + h] = cn;
      hh[e2] = sigm(go)*tanhf(cn);
      h1s[h] = hh[e2];
    }
    unsigned hw = (unsigned)f2b(hh[0]) | (((unsigned)f2b(hh[1])) << 16);
    *(unsigned*)(h1all + ((size_t)(t-1)*32 + b)*512 + h0i) = hw;
  } else {
    h1s[tid*2] = 0.f; h1s[tid*2+1] = 0.f;
  }
  __syncthreads();
  if (t >= T_) return;

  // att2 = h1(t-1)[b] @ Wd^T + bd  (GEMV, coalesced over n)
  {
    float acc = bdv[tid];
    const unsigned* wp = Wd2 + tid;
    #pragma unroll 8
    for (int kp=0; kp<256; ++kp){
      unsigned wv = wp[(size_t)kp << 8];
      acc += h1s[2*kp]   * b2f((u16)(wv & 0xFFFFu))
           + h1s[2*kp+1] * b2f((u16)(wv >> 16));
    }
    a2[tid] = acc;
  }
  __syncthreads();
  // e scores (wave wid handles 49 pixels)
  for (int pi = 0; pi < 49; ++pi){
    int p = wid*49 + pi;
    ushort4 av4 = *(const ushort4*)(att1b + (size_t)(b*P_ + p)*A_ + l*4);
    int j0 = l*4;
    float sum = fmaxf(b2f(av4.x)+a2[j0],  0.f)*wfv[j0]
              + fmaxf(b2f(av4.y)+a2[j0+1],0.f)*wfv[j0+1]
              + fmaxf(b2f(av4.z)+a2[j0+2],0.f)*wfv[j0+2]
              + fmaxf(b2f(av4.w)+a2[j0+3],0.f)*wfv[j0+3];
    #pragma unroll
    for (int off=32; off; off>>=1) sum += __shfl_xor(sum, off, 64);
    if (l == 0) ev[p] = sum + bf0;
  }
  __syncthreads();
  float v = (tid < P_) ? ev[tid] : -1e30f;
  float m = v;
  #pragma unroll
  for (int off=32; off; off>>=1) m = fmaxf(m, __shfl_xor(m, off, 64));
  if (l == 0) red[wid] = m;
  __syncthreads();
  m = fmaxf(fmaxf(red[0],red[1]), fmaxf(red[2],red[3]));
  float ex = (tid < P_) ? __expf(v - m) : 0.f;
  __syncthreads();
  ev[tid] = ex;
  float ss = ex;
  #pragma unroll
  for (int off=32; off; off>>=1) ss += __shfl_xor(ss, off, 64);
  if (l == 0) red[4+wid] = ss;
  __syncthreads();
  float inv = 1.f/(red[4]+red[5]+red[6]+red[7]);
  // ctx: thread handles bf16 column-pair tid
  {
    float acc0 = 0.f, acc1 = 0.f;
    const unsigned* ep = (const unsigned*)(enc16 + (size_t)b*P_*E_) + tid;
    for (int p = 0; p < P_; ++p){
      unsigned vv = ep[(size_t)p*256];
      float al = ev[p];
      acc0 += al * b2f((u16)(vv & 0xFFFFu));
      acc1 += al * b2f((u16)(vv >> 16));
    }
    unsigned o = (unsigned)f2b(acc0*inv) | ((unsigned)f2b(acc1*inv) << 16);
    *((unsigned*)(xh0cur + (size_t)b*1536 + 512) + tid) = o;
  }
  // emb_t copy
  ((unsigned*)(xh0cur + (size_t)b*1536))[tid] =
      ((const unsigned*)(embs + (size_t)(t*32+b)*E_))[tid];
}

// ---------------- LX: gates0(t)+cell0 -> h0(t) slice; gates1 k-slice partials ----------------
// block = h-slice s (16 h-values: h = s*16 + c).
__launch_bounds__(256)
__global__ void k_lx(const u16* __restrict__ xh0cur, u16* __restrict__ xh0nxt,
                     const u16* __restrict__ Wg0pk, const float* __restrict__ bias0p,
                     const u16* __restrict__ W1ppk, const u16* __restrict__ h1all,
                     float* __restrict__ c0buf, float* __restrict__ part1, int t){
  __shared__ float part[4][32][16];
  __shared__ float gsum[4][32][16];
  __shared__ __align__(16) u16 As[32][40];   // [b][ k<16: h0 slice | 16..31: h1 slice ]
  int tid = threadIdx.x, s = blockIdx.x;
  int l = tid & 63, kw = tid >> 6, lr = l & 15, lg = l >> 4;

  // gates0 (K=1536, A = [emb|ctx|h0prev])
  bf16x8 a[2][12];
  #pragma unroll
  for (int mi=0;mi<2;mi++)
    #pragma unroll
    for (int ks=0;ks<12;ks++)
      a[mi][ks] = *(const bf16x8*)(xh0cur + (size_t)(mi*16+lr)*1536 + kw*384 + ks*32 + lg*8);
  for (int q=0;q<4;q++){
    fx4 acc0 = (fx4){0,0,0,0}, acc1 = (fx4){0,0,0,0};
    const u16* wp = Wg0pk + (size_t)(((s*4+q)*4+kw)*12)*512 + l*8;
    #pragma unroll
    for (int ks=0;ks<12;ks++){
      bf16x8 bf8 = *(const bf16x8*)(wp + ks*512);
      acc0 = MFMA16(a[0][ks], bf8, acc0, 0,0,0);
      acc1 = MFMA16(a[1][ks], bf8, acc1, 0,0,0);
    }
    #pragma unroll
    for (int reg=0;reg<4;reg++){
      part[kw][lg*4+reg][lr]    = acc0[reg];
      part[kw][16+lg*4+reg][lr] = acc1[reg];
    }
    __syncthreads();
    #pragma unroll
    for (int pp=0;pp<2;pp++){
      int pid = tid + pp*256, bb = pid >> 4, c = pid & 15;
      gsum[q][bb][c] = part[0][bb][c]+part[1][bb][c]+part[2][bb][c]+part[3][bb][c]
                     + bias0p[s*64 + q*16 + c];
    }
    __syncthreads();
  }
  // stage h1(t-1) slice into As[b][16..32)
  {
    int b = tid >> 3, kk = (tid & 7)*2;
    unsigned hv = 0;
    if (t > 0) hv = *(const unsigned*)(h1all + ((size_t)(t-1)*32 + b)*512 + s*16 + kk);
    *(unsigned*)&As[b][16+kk] = hv;
  }
  // cell0 -> h0(t) slice: write to next xh0 buffer + As[b][0..16)
  {
    int bb = tid >> 3, c2 = (tid & 7)*2;
    int h = s*16 + c2;
    float gi0=gsum[0][bb][c2],   gf0=gsum[1][bb][c2],   gg0=gsum[2][bb][c2],   go0=gsum[3][bb][c2];
    float gi1=gsum[0][bb][c2+1], gf1=gsum[1][bb][c2+1], gg1=gsum[2][bb][c2+1], go1=gsum[3][bb][c2+1];
    float* cp = c0buf + bb*512 + h;
    float cn0 = sigm(gf0)*cp[0] + sigm(gi0)*tanhf(gg0);
    float cn1 = sigm(gf1)*cp[1] + sigm(gi1)*tanhf(gg1);
    cp[0] = cn0; cp[1] = cn1;
    unsigned hw = (unsigned)f2b(sigm(go0)*tanhf(cn0)) | (((unsigned)f2b(sigm(go1)*tanhf(cn1)))<<16);
    *(unsigned*)(xh0nxt + (size_t)bb*1536 + 1024 + h) = hw;
    *(unsigned*)&As[bb][c2] = hw;
  }
  __syncthreads();
  // gates1 partials: part1[s][b][n'] = [h0slice|h1slice](K=32) @ W1p[n'][K=32]^T
  bf16x8 pa0 = *(const bf16x8*)&As[lr][lg*8];
  bf16x8 pa1 = *(const bf16x8*)&As[16+lr][lg*8];
  #pragma unroll 2
  for (int i=0;i<32;i++){
    int nf = kw*32 + i;
    bf16x8 bf8 = *(const bf16x8*)(W1ppk + (size_t)(s*128 + nf)*512 + l*8);
    fx4 A0 = MFMA16(pa0, bf8, (fx4){0,0,0,0}, 0,0,0);
    fx4 A1 = MFMA16(pa1, bf8, (fx4){0,0,0,0}, 0,0,0);
    float* o = part1 + ((size_t)s*32)*2048 + nf*16 + lr;
    #pragma unroll
    for (int reg=0;reg<4;reg++){
      o[(size_t)(lg*4+reg)*2048]    = A0[reg];
      o[(size_t)(16+lg*4+reg)*2048] = A1[reg];
    }
  }
}

extern "C" void kernel_launch(void* const* d_in, const int* in_sizes, int n_in,
                              void* d_out, int out_size, void* d_ws, size_t ws_size,
                              hipStream_t stream){
  (void)in_sizes; (void)n_in; (void)out_size; (void)ws_size;
  const float* features = (const float*)d_in[0];
  const int*   captions = (const int*)d_in[1];
  const float* Wad  = (const float*)d_in[2];
  const float* bad  = (const float*)d_in[3];
  const float* g_ad = (const float*)d_in[4];
  const float* b_ad = (const float*)d_in[5];
  const float* We   = (const float*)d_in[6];
  const float* be   = (const float*)d_in[7];
  const float* Wd   = (const float*)d_in[8];
  const float* bd   = (const float*)d_in[9];
  const float* Wf   = (const float*)d_in[10];
  const float* bfp  = (const float*)d_in[11];
  const float* emb  = (const float*)d_in[12];
  const float* W_ih0 = (const float*)d_in[13];
  const float* W_hh0 = (const float*)d_in[14];
  const float* b_ih0 = (const float*)d_in[15];
  const float* b_hh0 = (const float*)d_in[16];
  const float* W_ih1 = (const float*)d_in[17];
  const float* W_hh1 = (const float*)d_in[18];
  const float* b_ih1 = (const float*)d_in[19];
  const float* b_hh1 = (const float*)d_in[20];
  const float* W1  = (const float*)d_in[21];
  const float* b1  = (const float*)d_in[22];
  const float* g1  = (const float*)d_in[23];
  const float* bb1 = (const float*)d_in[24];
  const float* W2  = (const float*)d_in[25];
  const float* b2  = (const float*)d_in[26];
  float* out = (float*)d_out;

  char* wsb = (char*)d_ws;
  size_t off = 0;
  auto alloc = [&](size_t bytes)->char*{
    char* p = wsb + off; off += (bytes + 255) & ~(size_t)255; return p;
  };
  u16* fb16    = (u16*)alloc((size_t)6272*2048*2);
  u16* Wad16   = (u16*)alloc((size_t)512*2048*2);
  u16* We16    = (u16*)alloc((size_t)256*512*2);
  u16* W1_16   = (u16*)alloc((size_t)256*512*2);
  u16* W2_16   = (u16*)alloc((size_t)30000*256*2);
  unsigned* Wd2 = (unsigned*)alloc((size_t)256*256*4);
  u16* Wg0pk   = (u16*)alloc((size_t)2048*1536*2);
  u16* W1ppk   = (u16*)alloc((size_t)32*128*512*2);
  float* bias0p = (float*)alloc(2048*4);
  float* bias1p = (float*)alloc(2048*4);
  u16* embs16  = (u16*)alloc((size_t)1024*512*2);
  u16* pre16   = (u16*)alloc((size_t)6272*512*2);
  u16* enc16   = (u16*)alloc((size_t)6272*512*2);
  u16* att1_16 = (u16*)alloc((size_t)6272*256*2);
  u16* xh0     = (u16*)alloc((size_t)2*32*1536*2);   // zeroed region start
  float* c0buf = (float*)alloc(32*512*4);
  float* c1buf = (float*)alloc(32*512*4);            // zeroed region end
  float* part1 = (float*)alloc((size_t)32*32*2048*4);
  u16* h1all16 = (u16*)alloc((size_t)1024*512*2);
  float* pre1  = (float*)alloc((size_t)1024*256*4);
  u16* hid16   = (u16*)alloc((size_t)1024*256*2);

  auto cdiv = [](int a, int b){ return (a+b-1)/b; };

  // zero recurrent state (xh0 196608 + c0 65536 + c1 65536, contiguous)
  hipMemsetAsync(xh0, 0, 196608 + 65536 + 65536, stream);

  // prep
  k_convert<<<cdiv(6272*2048/8,256),256,0,stream>>>(features, fb16, 6272*2048/8);
  k_convert<<<cdiv(512*2048/8,256),256,0,stream>>>(Wad, Wad16, 512*2048/8);
  k_convert<<<cdiv(256*512/8,256),256,0,stream>>>(We, We16, 256*512/8);
  k_convert<<<cdiv(256*512/8,256),256,0,stream>>>(W1, W1_16, 256*512/8);
  k_convert<<<cdiv(30000*256/8,256),256,0,stream>>>(W2, W2_16, 30000*256/8);
  k_pack_wd2<<<cdiv(256*256,256),256,0,stream>>>(Wd, Wd2);
  k_pack_g0<<<cdiv(6144*512,256),256,0,stream>>>(W_ih0, W_hh0, Wg0pk);
  k_pack_w1p<<<cdiv(32*128*512,256),256,0,stream>>>(W_ih1, W_hh1, W1ppk);
  k_bias_pack<<<8,256,0,stream>>>(b_ih0, b_hh0, bias0p);
  k_bias_pack<<<8,256,0,stream>>>(b_ih1, b_hh1, bias1p);
  k_gather<<<1024,64,0,stream>>>(emb, captions, embs16);

  // encoder
  k_gemm<0,64><<<dim3(8,49),256,0,stream>>>(fb16, Wad16, bad, nullptr, pre16, 6272, 512, 2048);
  k_ln1<<<6272,64,0,stream>>>(pre16, g_ad, b_ad, enc16);
  k_gemm<1,64><<<dim3(4,49),256,0,stream>>>(enc16, We16, be, nullptr, att1_16, 6272, 256, 512);

  // recurrence: 2 launches/step, all sync via kernel boundaries
  u16* xb[2] = { xh0, xh0 + 32*1536 };
  for (int t = 0; t < T_; ++t){
    k_ly<<<32,256,0,stream>>>(part1, bias1p, c1buf, h1all16, Wd2, bd,
                              att1_16, enc16, Wf, bfp, embs16, xb[t&1], t);
    k_lx<<<32,256,0,stream>>>(xb[t&1], xb[1-(t&1)], Wg0pk, bias0p,
                              W1ppk, h1all16, c0buf, part1, t);
  }
  // final finish: h1(31) -> h1all
  k_ly<<<32,256,0,stream>>>(part1, bias1p, c1buf, h1all16, Wd2, bd,
                            att1_16, enc16, Wf, bfp, embs16, xb[0], T_);

  // batched output head
  k_gemm<2,64><<<dim3(4,8),256,0,stream>>>(h1all16, W1_16, b1, pre1, nullptr, 1024, 256, 512);
  k_ln2<<<1024,64,0,stream>>>(pre1, g1, bb1, hid16);
  k_gemm<3,128><<<dim3(235,8),256,0,stream>>>(hid16, W2_16, b2, out, nullptr, 1024, 30000, 256);
}

// Round 6
// 1395.116 us; speedup vs baseline: 2.3260x; 1.8253x over previous
//
#include <hip/hip_runtime.h>

#define B_ 32
#define P_ 196
#define T_ 32
#define E_ 512
#define H_ 512
#define A_ 256
#define V_ 30000
#define FEAT_ 2048

typedef unsigned short u16;
typedef __attribute__((ext_vector_type(8))) short bf16x8;   // 8 bf16 = 4 VGPR
typedef __attribute__((ext_vector_type(4))) float fx4;

#define MFMA16 __builtin_amdgcn_mfma_f32_16x16x32_bf16

__device__ __forceinline__ u16 f2b(float f){
  unsigned u = __builtin_bit_cast(unsigned, f);
  u += 0x7FFFu + ((u >> 16) & 1u);
  return (u16)(u >> 16);
}
__device__ __forceinline__ float b2f(u16 h){
  unsigned u = ((unsigned)h) << 16;
  return __builtin_bit_cast(float, u);
}
__device__ __forceinline__ float sigm(float x){ return 1.f/(1.f + __expf(-x)); }

// ---------------- f32 -> bf16 convert ----------------
__global__ void k_convert(const float* __restrict__ src, u16* __restrict__ dst, int n8){
  int i = blockIdx.x*256 + threadIdx.x;
  if (i >= n8) return;
  const float4* s = (const float4*)src + (size_t)i*2;
  float4 a = s[0], b = s[1];
  ushort4* d = (ushort4*)dst + (size_t)i*2;
  d[0] = make_ushort4(f2b(a.x), f2b(a.y), f2b(a.z), f2b(a.w));
  d[1] = make_ushort4(f2b(b.x), f2b(b.y), f2b(b.z), f2b(b.w));
}

// ---------------- embedding gather -> bf16, row r = t*32+b ----------------
__global__ void k_gather(const float* __restrict__ emb, const int* __restrict__ cap,
                         u16* __restrict__ dst){
  int r = blockIdx.x, l = threadIdx.x;
  int t = r >> 5, b = r & 31;
  int c = cap[b*T_ + t];
  const float4* s = (const float4*)(emb + (size_t)c*E_) + l*2;
  float4 a = s[0], bb = s[1];
  ushort4* d = (ushort4*)(dst + (size_t)r*E_) + l*2;
  d[0] = make_ushort4(f2b(a.x), f2b(a.y), f2b(a.z), f2b(a.w));
  d[1] = make_ushort4(f2b(bb.x), f2b(bb.y), f2b(bb.z), f2b(bb.w));
}

// ---------------- Wd [256n][512k] -> Wd2[kp][n] u32 of (bf16 k=2kp, k=2kp+1) ----------------
__global__ void k_pack_wd2(const float* __restrict__ Wd, unsigned* __restrict__ dst){
  int i = blockIdx.x*256 + threadIdx.x;
  if (i >= 256*256) return;
  int n = i & 255, kp = i >> 8;
  unsigned lo = f2b(Wd[n*512 + 2*kp]);
  unsigned hi = f2b(Wd[n*512 + 2*kp + 1]);
  dst[i] = lo | (hi << 16);
}

// ---------------- pack layer-0 gate weights (permuted rows), K=1536 ----------------
// permuted col n' = s*64+q*16+r  <->  orig row = q*512+s*16+r
__global__ void k_pack_g0(const float* __restrict__ Wih, const float* __restrict__ Whh,
                          u16* __restrict__ dst){
  int eid = blockIdx.x*256 + threadIdx.x;
  if (eid >= 6144*512) return;
  int j = eid & 7, l = (eid >> 3) & 63, frag = eid >> 9;
  int ks = frag % 12; int rest = frag / 12;
  int kw = rest & 3, q = (rest >> 2) & 3, s = rest >> 4;
  int n = q*512 + s*16 + (l & 15);
  int k = kw*384 + ks*32 + ((l >> 4) << 3) + j;
  float v = (k < 1024) ? Wih[(size_t)n*1024 + k] : Whh[(size_t)n*512 + (k - 1024)];
  dst[eid] = f2b(v);
}

// ---------------- pack layer-1 partial weights, per-slice K=32 frags ----------------
__global__ void k_pack_w1p(const float* __restrict__ Wih, const float* __restrict__ Whh,
                           u16* __restrict__ dst){
  int eid = blockIdx.x*256 + threadIdx.x;
  if (eid >= 32*128*512) return;
  int j = eid & 7, l = (eid >> 3) & 63, f = eid >> 9;
  int nf = f & 127, s = f >> 7;
  int np = nf*16 + (l & 15);
  int k = ((l >> 4) << 3) + j;
  int orig = ((np >> 4) & 3)*512 + (np >> 6)*16 + (np & 15);
  float v = (k < 16) ? Wih[(size_t)orig*512 + s*16 + k]
                     : Whh[(size_t)orig*512 + s*16 + (k - 16)];
  dst[eid] = f2b(v);
}

// ---------------- permuted bias: b_ih + b_hh ----------------
__global__ void k_bias_pack(const float* __restrict__ bih, const float* __restrict__ bhh,
                            float* __restrict__ dst){
  int n = blockIdx.x*256 + threadIdx.x;
  if (n >= 2048) return;
  int c = n & 15, q = (n >> 4) & 3, s = n >> 6;
  int orig = q*512 + s*16 + c;
  dst[n] = bih[orig] + bhh[orig];
}

// ---------------- generic bf16 MFMA GEMM: C = A[M,K] @ W[N,K]^T + bias ----------------
// MODE 0: relu->bf16  1: ->bf16  2: ->f32  3: clip±10 -> f32
template<int MODE, int BM, int BN>
__launch_bounds__(256)
__global__ void k_gemm(const u16* __restrict__ A, const u16* __restrict__ W,
                       const float* __restrict__ bias, float* __restrict__ outF,
                       u16* __restrict__ outB, int M, int N, int K){
  constexpr int NI = BN/32, MI = BM/32;
  __shared__ __align__(16) u16 As[BM][40];
  __shared__ __align__(16) u16 Bs[BN][40];
  int tid = threadIdx.x;
  int l = tid & 63, w = tid >> 6;
  int wr = w >> 1, wc = w & 1;
  int m0 = blockIdx.y * BM, n0 = blockIdx.x * BN;
  fx4 acc[MI][NI];
  #pragma unroll
  for (int i=0;i<MI;i++)
    #pragma unroll
    for (int j=0;j<NI;j++) acc[i][j] = (fx4){0.f,0.f,0.f,0.f};
  int r = tid >> 2, seg = tid & 3;
  int lr = l & 15, lg = l >> 4;
  for (int k0 = 0; k0 < K; k0 += 32){
    #pragma unroll
    for (int pa=0; pa<BM/64; pa++)
      *(uint4*)&As[r+pa*64][seg*8] = *(const uint4*)(A + (size_t)(m0+r+pa*64)*K + k0 + seg*8);
    uint4 z = {0u,0u,0u,0u};
    #pragma unroll
    for (int pb=0; pb<BN/64; pb++){
      int rb = n0 + r + pb*64;
      *(uint4*)&Bs[r+pb*64][seg*8] = (rb < N) ? *(const uint4*)(W + (size_t)rb*K + k0 + seg*8) : z;
    }
    __syncthreads();
    bf16x8 av[MI], bv[NI];
    #pragma unroll
    for (int mi=0; mi<MI; mi++) av[mi] = *(const bf16x8*)&As[wr*(BM/2) + mi*16 + lr][lg*8];
    #pragma unroll
    for (int ni=0; ni<NI; ni++) bv[ni] = *(const bf16x8*)&Bs[wc*(BN/2) + ni*16 + lr][lg*8];
    #pragma unroll
    for (int mi=0; mi<MI; mi++)
      #pragma unroll
      for (int ni=0; ni<NI; ni++)
        acc[mi][ni] = MFMA16(av[mi], bv[ni], acc[mi][ni], 0, 0, 0);
    __syncthreads();
  }
  #pragma unroll
  for (int mi=0; mi<MI; mi++)
    #pragma unroll
    for (int ni=0; ni<NI; ni++){
      int col = n0 + wc*(BN/2) + ni*16 + lr;
      if (col >= N) continue;
      float bvs = bias[col];
      #pragma unroll
      for (int reg=0; reg<4; reg++){
        int rowm = m0 + wr*(BM/2) + mi*16 + lg*4 + reg;
        float v = acc[mi][ni][reg] + bvs;
        if (MODE == 0){ v = fmaxf(v, 0.f); outB[(size_t)rowm*N + col] = f2b(v); }
        else if (MODE == 1){ outB[(size_t)rowm*N + col] = f2b(v); }
        else if (MODE == 2){ outF[(size_t)rowm*N + col] = v; }
        else {
          v = fminf(fmaxf(v, -10.f), 10.f);
          outF[(size_t)rowm*V_ + col] = v;
        }
      }
    }
}

// ---------------- LayerNorm over 512 (bf16 in/out) ----------------
__global__ void k_ln1(const u16* __restrict__ pre, const float* __restrict__ g,
                      const float* __restrict__ bt, u16* __restrict__ enc){
  int row = blockIdx.x; int l = threadIdx.x;
  bf16x8 vv = *(const bf16x8*)(pre + (size_t)row*E_ + l*8);
  float x[8]; float s = 0.f;
  #pragma unroll
  for (int i=0;i<8;i++){ x[i] = b2f((u16)vv[i]); s += x[i]; }
  #pragma unroll
  for (int off=32; off; off>>=1) s += __shfl_xor(s, off, 64);
  float mean = s * (1.f/512.f);
  float vs = 0.f;
  #pragma unroll
  for (int i=0;i<8;i++){ float d = x[i]-mean; vs += d*d; }
  #pragma unroll
  for (int off=32; off; off>>=1) vs += __shfl_xor(vs, off, 64);
  float inv = rsqrtf(vs*(1.f/512.f) + 1e-5f);
  int c0 = l*8;
  u16 o[8];
  #pragma unroll
  for (int i=0;i<8;i++) o[i] = f2b((x[i]-mean)*inv*g[c0+i] + bt[c0+i]);
  ushort4* d = (ushort4*)(enc + (size_t)row*E_ + c0);
  d[0] = make_ushort4(o[0],o[1],o[2],o[3]);
  d[1] = make_ushort4(o[4],o[5],o[6],o[7]);
}

// ---------------- LayerNorm over 256 + relu (f32 in, bf16 out) ----------------
__global__ void k_ln2(const float* __restrict__ pre1, const float* __restrict__ g,
                      const float* __restrict__ bb, u16* __restrict__ hid){
  int row = blockIdx.x; int l = threadIdx.x;
  float4 v = *(const float4*)(pre1 + (size_t)row*256 + l*4);
  float x[4] = {v.x, v.y, v.z, v.w};
  float s = x[0]+x[1]+x[2]+x[3];
  #pragma unroll
  for (int off=32; off; off>>=1) s += __shfl_xor(s, off, 64);
  float mean = s * (1.f/256.f);
  float vs = 0.f;
  #pragma unroll
  for (int i=0;i<4;i++){ float d = x[i]-mean; vs += d*d; }
  #pragma unroll
  for (int off=32; off; off>>=1) vs += __shfl_xor(vs, off, 64);
  float inv = rsqrtf(vs*(1.f/256.f) + 1e-5f);
  int c0 = l*4;
  u16 o[4];
  #pragma unroll
  for (int i=0;i<4;i++) o[i] = f2b(fmaxf((x[i]-mean)*inv*g[c0+i] + bb[c0+i], 0.f));
  *(ushort4*)(hid + (size_t)row*256 + c0) = make_ushort4(o[0],o[1],o[2],o[3]);
}

// ---------------- LY: finish gates1(t-1)->h1; att2; attention; write [emb|ctx] ----------------
// block = batch b, 1024 threads (16 waves).
__launch_bounds__(1024)
__global__ void k_ly(const float* __restrict__ part1, const float* __restrict__ bias1p,
                     float* __restrict__ c1buf, u16* __restrict__ h1all,
                     const unsigned* __restrict__ Wd2, const float* __restrict__ bd,
                     const u16* __restrict__ att1b, const u16* __restrict__ enc16,
                     const float* __restrict__ Wf, const float* __restrict__ bfp,
                     const u16* __restrict__ embs, u16* __restrict__ xh0cur, int t){
  int b = blockIdx.x, tid = threadIdx.x;
  int l = tid & 63, wid = tid >> 6;
  __shared__ float g1s[2048];
  __shared__ float h1s[512];
  __shared__ float a2p[4][256];
  __shared__ float a2[256], ev[256], red[8], wfv[256], bdv[256];
  __shared__ float cb[4][256][2];
  if (tid < 256){ wfv[tid] = Wf[tid]; bdv[tid] = bd[tid]; }
  float bf0 = bfp[0];

  if (t > 0){
    float acc0 = bias1p[tid], acc1 = bias1p[tid + 1024];
    #pragma unroll 4
    for (int s2=0; s2<32; ++s2){
      const float* pp = part1 + ((size_t)(s2*32 + b))*2048;
      acc0 += pp[tid];
      acc1 += pp[tid + 1024];
    }
    g1s[tid] = acc0; g1s[tid + 1024] = acc1;
    __syncthreads();
    if (tid < 512){
      int h = tid, s4 = h >> 4, c = h & 15, base = s4*64 + c;
      float gi = g1s[base], gf = g1s[base+16], gg = g1s[base+32], go = g1s[base+48];
      float cold = c1buf[b*512 + h];
      float cn = sigm(gf)*cold + sigm(gi)*tanhf(gg);
      c1buf[b*512 + h] = cn;
      float hn = sigm(go)*tanhf(cn);
      h1s[h] = hn;
      h1all[((size_t)b*T_ + (t-1))*512 + h] = f2b(hn);
    }
  } else {
    if (tid < 512) h1s[tid] = 0.f;
  }
  __syncthreads();
  if (t >= T_) return;

  // att2 = h1 @ Wd^T + bd : thread (n = tid&255, kq = tid>>8), 4-way k-split
  {
    int n = tid & 255, kq = tid >> 8;
    float acc = 0.f;
    const unsigned* wp = Wd2 + (size_t)kq*64*256 + n;
    #pragma unroll 8
    for (int kp2 = 0; kp2 < 64; ++kp2){
      unsigned wv = wp[(size_t)kp2*256];
      int k0 = (kq*64 + kp2)*2;
      acc += h1s[k0]   * b2f((u16)(wv & 0xFFFFu))
           + h1s[k0+1] * b2f((u16)(wv >> 16));
    }
    a2p[kq][n] = acc;
  }
  __syncthreads();
  if (tid < 256) a2[tid] = a2p[0][tid] + a2p[1][tid] + a2p[2][tid] + a2p[3][tid] + bdv[tid];
  __syncthreads();
  // e scores: 16 waves, p = pi*16 + wid
  for (int pi = 0; pi < 13; ++pi){
    int p = pi*16 + wid;
    if (p < P_){
      ushort4 av4 = *(const ushort4*)(att1b + (size_t)(b*P_ + p)*A_ + l*4);
      int j0 = l*4;
      float sum = fmaxf(b2f(av4.x)+a2[j0],  0.f)*wfv[j0]
                + fmaxf(b2f(av4.y)+a2[j0+1],0.f)*wfv[j0+1]
                + fmaxf(b2f(av4.z)+a2[j0+2],0.f)*wfv[j0+2]
                + fmaxf(b2f(av4.w)+a2[j0+3],0.f)*wfv[j0+3];
      #pragma unroll
      for (int off=32; off; off>>=1) sum += __shfl_xor(sum, off, 64);
      if (l == 0) ev[p] = sum + bf0;
    }
  }
  __syncthreads();
  // softmax over 196 (first 4 waves)
  if (tid < 256){
    float v = (tid < P_) ? ev[tid] : -1e30f;
    float m = v;
    #pragma unroll
    for (int off=32; off; off>>=1) m = fmaxf(m, __shfl_xor(m, off, 64));
    if (l == 0) red[wid] = m;
  }
  __syncthreads();
  float mg = fmaxf(fmaxf(red[0],red[1]), fmaxf(red[2],red[3]));
  if (tid < 256){
    float ex = (tid < P_) ? __expf(ev[tid] - mg) : 0.f;
    float ss = ex;
    #pragma unroll
    for (int off=32; off; off>>=1) ss += __shfl_xor(ss, off, 64);
    if (l == 0) red[4+wid] = ss;
    ev[tid] = ex;
  }
  __syncthreads();
  float inv = 1.f/(red[4]+red[5]+red[6]+red[7]);
  // ctx: thread (j = tid&255, pq = tid>>8), 4-way pixel split (49 each)
  {
    int j = tid & 255, pq = tid >> 8;
    float A0 = 0.f, A1 = 0.f;
    const unsigned* ep = (const unsigned*)enc16 + ((size_t)b*P_ + pq*49)*256 + j;
    #pragma unroll 7
    for (int pi = 0; pi < 49; ++pi){
      unsigned vv = ep[(size_t)pi*256];
      float al = ev[pq*49 + pi];
      A0 += al * b2f((u16)(vv & 0xFFFFu));
      A1 += al * b2f((u16)(vv >> 16));
    }
    cb[pq][j][0] = A0; cb[pq][j][1] = A1;
  }
  __syncthreads();
  if (tid < 256){
    float c0 = (cb[0][tid][0]+cb[1][tid][0]+cb[2][tid][0]+cb[3][tid][0]) * inv;
    float c1 = (cb[0][tid][1]+cb[1][tid][1]+cb[2][tid][1]+cb[3][tid][1]) * inv;
    unsigned o = (unsigned)f2b(c0) | (((unsigned)f2b(c1)) << 16);
    *((unsigned*)(xh0cur + (size_t)b*1536 + 512) + tid) = o;
    // emb_t copy
    ((unsigned*)(xh0cur + (size_t)b*1536))[tid] =
        ((const unsigned*)(embs + (size_t)(t*32+b)*E_))[tid];
  }
}

// ---------------- LX: gates0(t)+cell0 -> h0(t) slice; gates1 k-slice partials ----------------
// block = h-slice s, 1024 threads (16 waves, 16-way k-split).
__launch_bounds__(1024)
__global__ void k_lx(const u16* __restrict__ xh0cur, u16* __restrict__ xh0nxt,
                     const u16* __restrict__ Wg0pk, const float* __restrict__ bias0p,
                     const u16* __restrict__ W1ppk, const u16* __restrict__ h1all,
                     float* __restrict__ c0buf, float* __restrict__ part1, int t){
  __shared__ float part[16][32][16];
  __shared__ float gsum[4][32][16];
  __shared__ __align__(16) u16 As[32][40];   // [b][ k<16: h0 slice | 16..31: h1 slice ]
  int tid = threadIdx.x, s = blockIdx.x;
  int l = tid & 63, kw = tid >> 6, lr = l & 15, lg = l >> 4;

  // gates0 (K=1536 = 16 waves x 96)
  bf16x8 a[2][3];
  #pragma unroll
  for (int mi=0;mi<2;mi++)
    #pragma unroll
    for (int ks=0;ks<3;ks++)
      a[mi][ks] = *(const bf16x8*)(xh0cur + (size_t)(mi*16+lr)*1536 + kw*96 + ks*32 + lg*8);
  for (int q=0;q<4;q++){
    fx4 acc0 = (fx4){0,0,0,0}, acc1 = (fx4){0,0,0,0};
    const u16* wp = Wg0pk + (size_t)(((s*4+q)*4 + (kw>>2))*12 + (kw&3)*3)*512 + l*8;
    #pragma unroll
    for (int ks=0;ks<3;ks++){
      bf16x8 bf8 = *(const bf16x8*)(wp + ks*512);
      acc0 = MFMA16(a[0][ks], bf8, acc0, 0,0,0);
      acc1 = MFMA16(a[1][ks], bf8, acc1, 0,0,0);
    }
    #pragma unroll
    for (int reg=0;reg<4;reg++){
      part[kw][lg*4+reg][lr]    = acc0[reg];
      part[kw][16+lg*4+reg][lr] = acc1[reg];
    }
    __syncthreads();
    if (tid < 512){
      int bb = tid >> 4, c = tid & 15;
      float g = bias0p[s*64 + q*16 + c];
      #pragma unroll
      for (int kw2=0; kw2<16; ++kw2) g += part[kw2][bb][c];
      gsum[q][bb][c] = g;
    }
    __syncthreads();
  }
  // stage h1(t-1) slice into As[b][16..32)
  if (tid < 256){
    int bb = tid >> 3, kk = (tid & 7)*2;
    unsigned hv = 0;
    if (t > 0) hv = *(const unsigned*)(h1all + ((size_t)bb*T_ + (t-1))*512 + s*16 + kk);
    *(unsigned*)&As[bb][16+kk] = hv;
  }
  // cell0 -> h0(t) slice
  if (tid < 512){
    int bb = tid >> 4, c = tid & 15;
    int h = s*16 + c;
    float gi = gsum[0][bb][c], gf = gsum[1][bb][c], gg = gsum[2][bb][c], go = gsum[3][bb][c];
    float cold = c0buf[bb*512 + h];
    float cn = sigm(gf)*cold + sigm(gi)*tanhf(gg);
    c0buf[bb*512 + h] = cn;
    u16 hb = f2b(sigm(go)*tanhf(cn));
    xh0nxt[(size_t)bb*1536 + 1024 + h] = hb;
    As[bb][c] = hb;
  }
  __syncthreads();
  // gates1 partials: 16 waves x 8 nf
  bf16x8 pa0 = *(const bf16x8*)&As[lr][lg*8];
  bf16x8 pa1 = *(const bf16x8*)&As[16+lr][lg*8];
  #pragma unroll 2
  for (int i=0;i<8;i++){
    int nf = kw*8 + i;
    bf16x8 bf8 = *(const bf16x8*)(W1ppk + (size_t)(s*128 + nf)*512 + l*8);
    fx4 A0 = MFMA16(pa0, bf8, (fx4){0,0,0,0}, 0,0,0);
    fx4 A1 = MFMA16(pa1, bf8, (fx4){0,0,0,0}, 0,0,0);
    float* o = part1 + ((size_t)s*32)*2048 + nf*16 + lr;
    #pragma unroll
    for (int reg=0;reg<4;reg++){
      o[(size_t)(lg*4+reg)*2048]    = A0[reg];
      o[(size_t)(16+lg*4+reg)*2048] = A1[reg];
    }
  }
}

extern "C" void kernel_launch(void* const* d_in, const int* in_sizes, int n_in,
                              void* d_out, int out_size, void* d_ws, size_t ws_size,
                              hipStream_t stream){
  (void)in_sizes; (void)n_in; (void)out_size; (void)ws_size;
  const float* features = (const float*)d_in[0];
  const int*   captions = (const int*)d_in[1];
  const float* Wad  = (const float*)d_in[2];
  const float* bad  = (const float*)d_in[3];
  const float* g_ad = (const float*)d_in[4];
  const float* b_ad = (const float*)d_in[5];
  const float* We   = (const float*)d_in[6];
  const float* be   = (const float*)d_in[7];
  const float* Wd   = (const float*)d_in[8];
  const float* bd   = (const float*)d_in[9];
  const float* Wf   = (const float*)d_in[10];
  const float* bfp  = (const float*)d_in[11];
  const float* emb  = (const float*)d_in[12];
  const float* W_ih0 = (const float*)d_in[13];
  const float* W_hh0 = (const float*)d_in[14];
  const float* b_ih0 = (const float*)d_in[15];
  const float* b_hh0 = (const float*)d_in[16];
  const float* W_ih1 = (const float*)d_in[17];
  const float* W_hh1 = (const float*)d_in[18];
  const float* b_ih1 = (const float*)d_in[19];
  const float* b_hh1 = (const float*)d_in[20];
  const float* W1  = (const float*)d_in[21];
  const float* b1  = (const float*)d_in[22];
  const float* g1  = (const float*)d_in[23];
  const float* bb1 = (const float*)d_in[24];
  const float* W2  = (const float*)d_in[25];
  const float* b2  = (const float*)d_in[26];
  float* out = (float*)d_out;

  char* wsb = (char*)d_ws;
  size_t off = 0;
  auto alloc = [&](size_t bytes)->char*{
    char* p = wsb + off; off += (bytes + 255) & ~(size_t)255; return p;
  };
  u16* fb16    = (u16*)alloc((size_t)6272*2048*2);
  u16* Wad16   = (u16*)alloc((size_t)512*2048*2);
  u16* We16    = (u16*)alloc((size_t)256*512*2);
  u16* W1_16   = (u16*)alloc((size_t)256*512*2);
  u16* W2_16   = (u16*)alloc((size_t)30000*256*2);
  unsigned* Wd2 = (unsigned*)alloc((size_t)256*256*4);
  u16* Wg0pk   = (u16*)alloc((size_t)2048*1536*2);
  u16* W1ppk   = (u16*)alloc((size_t)32*128*512*2);
  float* bias0p = (float*)alloc(2048*4);
  float* bias1p = (float*)alloc(2048*4);
  u16* embs16  = (u16*)alloc((size_t)1024*512*2);
  u16* pre16   = (u16*)alloc((size_t)6272*512*2);
  u16* enc16   = (u16*)alloc((size_t)6272*512*2);
  u16* att1_16 = (u16*)alloc((size_t)6272*256*2);
  u16* xh0     = (u16*)alloc((size_t)2*32*1536*2);   // zeroed region start
  float* c0buf = (float*)alloc(32*512*4);
  float* c1buf = (float*)alloc(32*512*4);            // zeroed region end
  float* part1 = (float*)alloc((size_t)32*32*2048*4);
  u16* h1all16 = (u16*)alloc((size_t)1024*512*2);
  float* pre1  = (float*)alloc((size_t)1024*256*4);
  u16* hid16   = (u16*)alloc((size_t)1024*256*2);

  auto cdiv = [](int a, int b){ return (a+b-1)/b; };

  // zero recurrent state (xh0 196608 + c0 65536 + c1 65536, contiguous)
  hipMemsetAsync(xh0, 0, 196608 + 65536 + 65536, stream);

  // prep
  k_convert<<<cdiv(6272*2048/8,256),256,0,stream>>>(features, fb16, 6272*2048/8);
  k_convert<<<cdiv(512*2048/8,256),256,0,stream>>>(Wad, Wad16, 512*2048/8);
  k_convert<<<cdiv(256*512/8,256),256,0,stream>>>(We, We16, 256*512/8);
  k_convert<<<cdiv(256*512/8,256),256,0,stream>>>(W1, W1_16, 256*512/8);
  k_convert<<<cdiv(30000*256/8,256),256,0,stream>>>(W2, W2_16, 30000*256/8);
  k_pack_wd2<<<cdiv(256*256,256),256,0,stream>>>(Wd, Wd2);
  k_pack_g0<<<cdiv(6144*512,256),256,0,stream>>>(W_ih0, W_hh0, Wg0pk);
  k_pack_w1p<<<cdiv(32*128*512,256),256,0,stream>>>(W_ih1, W_hh1, W1ppk);
  k_bias_pack<<<8,256,0,stream>>>(b_ih0, b_hh0, bias0p);
  k_bias_pack<<<8,256,0,stream>>>(b_ih1, b_hh1, bias1p);
  k_gather<<<1024,64,0,stream>>>(emb, captions, embs16);

  // encoder (BM=64 tiles for occupancy)
  k_gemm<0,64,64><<<dim3(8,98),256,0,stream>>>(fb16, Wad16, bad, nullptr, pre16, 6272, 512, 2048);
  k_ln1<<<6272,64,0,stream>>>(pre16, g_ad, b_ad, enc16);
  k_gemm<1,64,64><<<dim3(4,98),256,0,stream>>>(enc16, We16, be, nullptr, att1_16, 6272, 256, 512);

  // recurrence: 2 launches/step, 1024-thread blocks
  u16* xb[2] = { xh0, xh0 + 32*1536 };
  for (int t = 0; t < T_; ++t){
    k_ly<<<32,1024,0,stream>>>(part1, bias1p, c1buf, h1all16, Wd2, bd,
                               att1_16, enc16, Wf, bfp, embs16, xb[t&1], t);
    k_lx<<<32,1024,0,stream>>>(xb[t&1], xb[1-(t&1)], Wg0pk, bias0p,
                               W1ppk, h1all16, c0buf, part1, t);
  }
  // final finish: h1(31) -> h1all
  k_ly<<<32,1024,0,stream>>>(part1, bias1p, c1buf, h1all16, Wd2, bd,
                             att1_16, enc16, Wf, bfp, embs16, xb[0], T_);

  // batched output head (h1all is (b,t)-major -> coalesced output rows)
  k_gemm<2,64,64><<<dim3(4,16),256,0,stream>>>(h1all16, W1_16, b1, pre1, nullptr, 1024, 256, 512);
  k_ln2<<<1024,64,0,stream>>>(pre1, g1, bb1, hid16);
  k_gemm<3,64,128><<<dim3(235,16),256,0,stream>>>(hid16, W2_16, b2, out, nullptr, 1024, 30000, 256);
}